// Round 1
// baseline (481.753 us; speedup 1.0000x reference)
//
#include <hip/hip_runtime.h>

#define BATCH 256
#define SEQ_T 512
#define CIN   6
#define RES   256

// One workgroup (1024 threads) per batch row; loops over all T steps.
// Phase 1 (all 16 waves): r = tid&127 -> outputs {r, r+128}; kk = tid>>7 (0..7)
//   owns k-chunk [kk*32, kk*32+32); W slice register-resident (64 VGPRs).
// Phase 2 (threads 0..255): reduce 8 partials, add x@W_in, tanh, write.
__global__ __launch_bounds__(1024, 1)
void esn_scan_kernel(const float* __restrict__ x,
                     const float* __restrict__ W_in,
                     const float* __restrict__ W_res,
                     float* __restrict__ out) {
    __shared__ float h[2][RES];        // double-buffered state
    __shared__ float part[8][RES];     // partial sums

    const int tid = threadIdx.x;
    const int b   = blockIdx.x;
    const int r   = tid & 127;
    const int kk  = tid >> 7;

    // Register-resident W_res slice: w0[j] = W[(kk*32+j)][r], w1: column r+128.
    float w0[32], w1[32];
    #pragma unroll
    for (int j = 0; j < 32; ++j) {
        w0[j] = W_res[(kk * 32 + j) * RES + r];
        w1[j] = W_res[(kk * 32 + j) * RES + r + 128];
    }

    // Input-projection weights for the reduce threads.
    float win[CIN];
    if (tid < RES) {
        #pragma unroll
        for (int c = 0; c < CIN; ++c) win[c] = W_in[c * RES + tid];
    }

    if (tid < RES) h[0][tid] = 0.0f;
    __syncthreads();

    const float* xb = x + (size_t)b * SEQ_T * CIN;
    float*       ob = out + (size_t)b * SEQ_T * RES;

    int p = 0;
    for (int t = 0; t < SEQ_T; ++t) {
        // Uniform loads of this step's input (compiler scalarizes to s_load).
        float xv[CIN];
        #pragma unroll
        for (int c = 0; c < CIN; ++c) xv[c] = xb[t * CIN + c];

        // Phase 1: matvec partials. h chunk is wave-uniform -> LDS broadcast.
        const float4* hb = (const float4*)(&h[p][kk * 32]);
        float a0 = 0.0f, a1 = 0.0f;
        #pragma unroll
        for (int j = 0; j < 8; ++j) {
            float4 hv = hb[j];
            a0 = fmaf(hv.x, w0[4*j+0], a0); a1 = fmaf(hv.x, w1[4*j+0], a1);
            a0 = fmaf(hv.y, w0[4*j+1], a0); a1 = fmaf(hv.y, w1[4*j+1], a1);
            a0 = fmaf(hv.z, w0[4*j+2], a0); a1 = fmaf(hv.z, w1[4*j+2], a1);
            a0 = fmaf(hv.w, w0[4*j+3], a0); a1 = fmaf(hv.w, w1[4*j+3], a1);
        }
        part[kk][r]       = a0;
        part[kk][r + 128] = a1;
        __syncthreads();

        // Phase 2: reduce + input projection + tanh + state/output write.
        if (tid < RES) {
            float s = 0.0f;
            #pragma unroll
            for (int c = 0; c < CIN; ++c) s = fmaf(xv[c], win[c], s);
            #pragma unroll
            for (int q = 0; q < 8; ++q) s += part[q][tid];
            // tanh(s) = 1 - 2/(exp(2s)+1); robust at +/-inf saturation.
            float e  = __expf(2.0f * s);
            float hn = 1.0f - 2.0f * __builtin_amdgcn_rcpf(e + 1.0f);
            h[1 - p][tid]   = hn;
            ob[t * RES + tid] = hn;
        }
        __syncthreads();
        p ^= 1;
    }
}

extern "C" void kernel_launch(void* const* d_in, const int* in_sizes, int n_in,
                              void* d_out, int out_size, void* d_ws, size_t ws_size,
                              hipStream_t stream) {
    const float* x     = (const float*)d_in[0];
    const float* W_in  = (const float*)d_in[1];
    const float* W_res = (const float*)d_in[2];
    float*       out   = (float*)d_out;

    esn_scan_kernel<<<BATCH, 1024, 0, stream>>>(x, W_in, W_res, out);
}